// Round 21
// baseline (111.582 us; speedup 1.0000x reference)
//
#include <hip/hip_runtime.h>
#include <hip/hip_bf16.h>

// Shapes (fixed): B=2, S=2048, E=1024, H=16, D=64
// d_out: out[4194304] fp32 | k[4194304] fp32 [B,H,S,D] | v[4194304] fp32 [B,H,S,D]
// ws: x_bf | wT1 | wT2 | q_bf | k_bf | vT_bf ; o_bf aliases x_bf.

typedef __attribute__((ext_vector_type(4))) float f32x4;
typedef __attribute__((ext_vector_type(16))) float f32x16;
typedef __attribute__((ext_vector_type(8))) short s16x8;
typedef __attribute__((ext_vector_type(4))) short s16x4;

__device__ __forceinline__ short f2bf(float f) {
    union { float f; unsigned u; } x{f};
    unsigned r = x.u + 0x7fff + ((x.u >> 16) & 1);
    return (short)(r >> 16);
}

__device__ __forceinline__ void gload_lds16(const void* g, void* l) {
    __builtin_amdgcn_global_load_lds(
        (const __attribute__((address_space(1))) void*)g,
        (__attribute__((address_space(3))) void*)l, 16, 0, 0);
}

// ---------------- fused pre-pass (1 launch) ----------------
// blocks [0,2048):        x fp32 -> x_bf (8 elems/thread)
// blocks [2048,5120):     qkv_w [1024][3072] -> wT1 [3072][1024] bf16
// blocks [5120,6144):     proj_w [1024][1024] -> wT2 [1024][1024] bf16
__global__ __launch_bounds__(256) void fused_prepass(const float* __restrict__ x,
                                                     short* __restrict__ x_bf,
                                                     const float* __restrict__ qkv_w,
                                                     short* __restrict__ wT1,
                                                     const float* __restrict__ proj_w,
                                                     short* __restrict__ wT2) {
    __shared__ float tile[32][33];
    const int bid = blockIdx.x, tid = threadIdx.x;
    if (bid < 2048) {
        int i = (bid * 256 + tid) * 8;
        f32x4 a = *(const f32x4*)&x[i];
        f32x4 b = *(const f32x4*)&x[i + 4];
        s16x8 o;
        #pragma unroll
        for (int j = 0; j < 4; ++j) o[j] = f2bf(a[j]);
        #pragma unroll
        for (int j = 0; j < 4; ++j) o[j + 4] = f2bf(b[j]);
        *(s16x8*)&x_bf[i] = o;
        return;
    }
    const float* in;
    short* out;
    int K = 1024, N, n0, k0;
    if (bid < 5120) {
        int blk = bid - 2048;
        in = qkv_w; out = wT1; N = 3072;
        n0 = (blk % 96) * 32; k0 = (blk / 96) * 32;
    } else {
        int blk = bid - 5120;
        in = proj_w; out = wT2; N = 1024;
        n0 = (blk & 31) * 32; k0 = (blk >> 5) * 32;
    }
    const int tx = tid & 31, ty = tid >> 5;  // 32 x 8
    #pragma unroll
    for (int r = 0; r < 4; ++r)
        tile[ty + r * 8][tx] = in[(long)(k0 + ty + r * 8) * N + n0 + tx];
    __syncthreads();
    #pragma unroll
    for (int r = 0; r < 4; ++r)
        out[(long)(n0 + ty + r * 8) * K + k0 + tx] = f2bf(tile[tx][ty + r * 8]);
}

// ---------------- GEMM (128x128 tile, BK=64, DOUBLE-BUFFERED staging) ------------------
// A: [M][K] bf16, Bt: [N][K] bf16.  MODE 1: qkv epilogue (q/k/v scatter + vT). MODE 2: bias.
// ROUND-21: revert round-20's k-split (launch_bounds(512,4) forced VGPR 64 -> spills,
// WRITE +13 MB). Real flaw of the round-19 GEMM: `barrier; stage; barrier(drain); compute`
// exposes the FULL L2 latency of every stage. Fix = attn-proven pattern: double-buffer
// LDS (As/Bs x2 = 64 KB) and reorder to `barrier(drains stage(t)); issue stage(t+1);
// compute(buf[t])` -- stage(t+1) flies under ~500 cy of ds_read+MFMA, drain at the next
// barrier costs only the residual. One __syncthreads per k-iter.
// Chunk XOR-swizzle both-sides staging + fragment reads (round-17, proven).
// XCD patch swizzle: MODE1 12x8 patch/XCD, MODE2 4x8.
template <int MODE>
__global__ __launch_bounds__(256) void gemm_bf16(
    const short* __restrict__ A, const short* __restrict__ Bt,
    const float* __restrict__ bias, int M, int N, int K,
    float* __restrict__ outf,
    short* __restrict__ qbf, short* __restrict__ kbf, short* __restrict__ vbfT,
    float* __restrict__ kout, float* __restrict__ vout) {
    __shared__ __align__(16) short As[2][128 * 64];
    __shared__ __align__(16) short Bs[2][128 * 64];
    const int tid = threadIdx.x;
    const int l = tid & 63, w = tid >> 6;
    const int lr = l >> 4, lc = l & 15;
    const int wm = w >> 1, wn = w & 1;
    const int bid = blockIdx.x;
    const int xcd = bid & 7, s = bid >> 3;
    int bx, by;
    if (MODE == 1) { bx = (xcd & 1) * 12 + s % 12; by = (xcd >> 1) * 8 + s / 12; }
    else           { bx = (xcd & 1) * 4 + (s & 3); by = (xcd >> 1) * 8 + (s >> 2); }
    const int m0 = by * 128, n0 = bx * 128;

    f32x4 acc[4][4] = {};

    // stage: 1024 chunks of 16B per tile; thread handles chunks tid+256*j.
    // chunk c -> row c>>3, phys seg c&7 holds logical seg (c&7)^(row&7).
    auto stage = [&](int it, int nb) {
        const int kb = it * 64;
        #pragma unroll
        for (int j = 0; j < 4; ++j) {
            const int c = tid + 256 * j;
            const int row = c >> 3;
            const int lseg = (c & 7) ^ (row & 7);
            gload_lds16(A + (long)(m0 + row) * K + kb + lseg * 8, &As[nb][c * 8]);
            gload_lds16(Bt + (long)(n0 + row) * K + kb + lseg * 8, &Bs[nb][c * 8]);
        }
    };

    const int NIT = K >> 6;            // 16
    stage(0, 0);
    int cur = 0;

    for (int it = 0; it < NIT; ++it) {
        __syncthreads();               // drains stage(it); compute(it-1) readers done
        if (it + 1 < NIT) stage(it + 1, cur ^ 1);   // flies under compute(it)
        #pragma unroll
        for (int kh = 0; kh < 2; ++kh) {
            s16x8 af[4], bfr[4];
            #pragma unroll
            for (int mi = 0; mi < 4; ++mi) {
                const int row = wm * 64 + mi * 16 + lc;
                af[mi] = *(const s16x8*)&As[cur][row * 64 + (((kh * 4 + lr) ^ (lc & 7)) * 8)];
            }
            #pragma unroll
            for (int ni = 0; ni < 4; ++ni) {
                const int row = wn * 64 + ni * 16 + lc;
                bfr[ni] = *(const s16x8*)&Bs[cur][row * 64 + (((kh * 4 + lr) ^ (lc & 7)) * 8)];
            }
            #pragma unroll
            for (int mi = 0; mi < 4; ++mi)
                #pragma unroll
                for (int ni = 0; ni < 4; ++ni)
                    acc[mi][ni] = __builtin_amdgcn_mfma_f32_16x16x32_bf16(
                        af[mi], bfr[ni], acc[mi][ni], 0, 0, 0);
        }
        cur ^= 1;
    }

    #pragma unroll
    for (int mi = 0; mi < 4; ++mi) {
        #pragma unroll
        for (int ni = 0; ni < 4; ++ni) {
            int col = n0 + wn * 64 + ni * 16 + lc;
            float bv = bias[col];
            if (MODE == 1) {
                int sec = col >> 10, rem = col & 1023;
                int h = rem >> 6, d = rem & 63;
                int row0 = m0 + wm * 64 + mi * 16 + lr * 4;
                int b = row0 >> 11, s0 = row0 & 2047;
                long idxSD = ((long)((b << 4) + h) * 2048 + s0) * 64 + d;
                if (sec == 0) {
                    #pragma unroll
                    for (int i = 0; i < 4; ++i) {
                        float val = acc[mi][ni][i] + bv;
                        // bake attn scale 1/8 and log2(e) for exp2-domain softmax
                        qbf[idxSD + (long)i * 64] = f2bf(val * 0.1803368801111244f);
                    }
                } else if (sec == 1) {
                    #pragma unroll
                    for (int i = 0; i < 4; ++i) {
                        float val = acc[mi][ni][i] + bv;
                        kout[idxSD + (long)i * 64] = val;
                        kbf[idxSD + (long)i * 64] = f2bf(val);
                    }
                } else {
                    s16x4 pk;
                    #pragma unroll
                    for (int i = 0; i < 4; ++i) {
                        float val = acc[mi][ni][i] + bv;
                        vout[idxSD + (long)i * 64] = val;
                        pk[i] = f2bf(val);
                    }
                    *(s16x4*)&vbfT[((long)((b << 4) + h) * 64 + d) * 2048 + s0] = pk;
                }
            } else {
                #pragma unroll
                for (int i = 0; i < 4; ++i) {
                    int row = m0 + wm * 64 + mi * 16 + lr * 4 + i;
                    outf[(long)row * N + col] = acc[mi][ni][i] + bv;
                }
            }
        }
    }
}

// ---------------- flash attention (round-19: 8 waves, k-split + ADD merge) -------------
__global__ __launch_bounds__(512, 4) void attn_kernel(const short* __restrict__ qbf,
                                                      const short* __restrict__ kbf,
                                                      const short* __restrict__ vbfT,
                                                      short* __restrict__ obf) {
    const int bid = blockIdx.x;
    const int xcd = bid & 7, r = bid >> 3;      // 64 slots per XCD
    const int head_local = r & 3, q16 = r >> 2; // q16 in 0..15
    const int qt = (q16 < 8) ? (q16 + 8) : (15 - q16);  // CU slot-pair qt sums = 15
    const int bh = xcd * 4 + head_local;
    const int tid = threadIdx.x;
    const int wv = tid >> 6, l = tid & 63;      // wv in 0..7
    const int strip = wv & 3, kh = wv >> 2;     // q-strip, key-half
    const int h = l >> 5;                        // lane half
    const int l8 = l & 7;
    const int q0 = qt * 128 + strip * 32;        // this wave's 32-q strip
    const int qlane = q0 + (l & 31);
    const long baseSD = (long)bh * 2048 * 64;   // q,k: [S][64]
    const long baseDS = (long)bh * 64 * 2048;   // vT:  [64][S]

    __shared__ __align__(16) short Ks[2][64 * 64];  // swizzled K tile   (8 KB x2)
    __shared__ __align__(16) short Vs[2][64 * 64];  // swizzled V^T tile (8 KB x2)
    __shared__ __align__(16) float MG[4][64][36];   // merge: O[32] | lsum (36 KB, one-time)

    const int sSub = l >> 3;
    const int sChunk = (l & 7) ^ sSub;
    auto stage = [&](int kt, int nb) {
        const int k0 = kt * 64;
        const int r0 = wv * 8 + sSub;
        gload_lds16(kbf + baseSD + (long)(k0 + r0) * 64 + sChunk * 8,
                    &Ks[nb][(wv * 8) * 64]);
        gload_lds16(vbfT + baseDS + (long)r0 * 2048 + k0 + sChunk * 8,
                    &Vs[nb][(wv * 8) * 64]);
    };

    // Q fragments (B-operand, 32x32x16): lane holds col q = qlane, kdim d = dd*16 + h*8 + j
    s16x8 qf[4];
    #pragma unroll
    for (int dd = 0; dd < 4; ++dd)
        qf[dd] = *(const s16x8*)&qbf[baseSD + (long)qlane * 64 + dd * 16 + h * 8];

    f32x4 lacc = {};                   // 4 independent partial-sum accumulators
    f32x16 O[2] = {};                  // O^T: O[dt2][rr] = O[d = dt2*32+(rr&3)+8*(rr>>2)+4h][qlane]

    const int nkt = 2 * qt + 2;        // k-tiles covering rows 0..qt*128+127

    stage(0, 0);
    __syncthreads();                   // drains vmcnt -> buf0 ready
    int cur = 0;

    for (int kt = 0; kt < nkt; ++kt) {
        if (kt + 1 < nkt) stage(kt + 1, cur ^ 1);
        const int kbase = kt * 64 + kh * 32;   // this wave's 32-key half

        if (kbase <= q0 + 31) {        // half has unmasked keys for this strip
            const short* Kb = Ks[cur];
            const short* Vb = Vs[cur];
            // QK: S^T[32k x 32q] accumulated over d (keys kbase..kbase+31)
            f32x16 z = {};
            #pragma unroll
            for (int dd = 0; dd < 4; ++dd) {
                s16x8 kf = *(const s16x8*)&Kb[(kh * 32 + (l & 31)) * 64 +
                                              (((2 * dd + h) ^ l8) * 8)];
                z = __builtin_amdgcn_mfma_f32_32x32x16_bf16(kf, qf[dd], z, 0, 0, 0);
            }
            // causal mask: k = kbase + (rr&3)+8*(rr>>2)+4h, q = qlane
            if (kbase + 31 > q0) {
                #pragma unroll
                for (int rr = 0; rr < 16; ++rr) {
                    int kpos = kbase + (rr & 3) + 8 * (rr >> 2) + 4 * h;
                    if (kpos > qlane) z[rr] = -INFINITY;
                }
            }
            // static softmax: p = exp2(s'); exp2(-inf) = 0 handles the mask
            float p[16];
            #pragma unroll
            for (int rr = 0; rr < 16; ++rr) {
                p[rr] = __builtin_amdgcn_exp2f(z[rr]);
                lacc[rr & 3] += p[rr];
            }
            // PV per 16-k fragment f (k base fb = kh*32 + f*16), pi-permuted kdim:
            //   B = packed own p[f*8..f*8+7] via v_cvt_pk_bf16_f32 (builtin, RNE);
            //   A = V^T rows, two b64 at k = fb+4h and fb+8+4h.
            #pragma unroll
            for (int f = 0; f < 2; ++f) {
                union { __hip_bfloat162 b2[4]; s16x8 v; } pk;
                #pragma unroll
                for (int j = 0; j < 4; ++j)
                    pk.b2[j] = __float22bfloat162_rn(
                        make_float2(p[f * 8 + 2 * j], p[f * 8 + 2 * j + 1]));
                const int c0 = kh * 4 + f * 2;        // logical chunk of fb
                #pragma unroll
                for (int dt2 = 0; dt2 < 2; ++dt2) {
                    const short* vr = &Vb[(dt2 * 32 + (l & 31)) * 64];
                    s16x8 vf;
                    *(s16x4*)&vf = *(const s16x4*)&vr[(c0 ^ l8) * 8 + 4 * h];
                    *(((s16x4*)&vf) + 1) = *(const s16x4*)&vr[((c0 + 1) ^ l8) * 8 + 4 * h];
                    O[dt2] = __builtin_amdgcn_mfma_f32_32x32x16_bf16(vf, pk.v,
                                                                     O[dt2], 0, 0, 0);
                }
            }
        }
        __syncthreads();               // all done with buf[cur]; stage(kt+1) drained
        cur ^= 1;
    }

    // ---- k-half merge (pure ADD: static softmax => O, lsum are sums over k) ----
    float lsum = (lacc[0] + lacc[1]) + (lacc[2] + lacc[3]);
    if (kh == 1) {
        float* row = &MG[strip][l][0];
        #pragma unroll
        for (int dt2 = 0; dt2 < 2; ++dt2)
            #pragma unroll
            for (int rr = 0; rr < 16; ++rr)
                row[dt2 * 16 + rr] = O[dt2][rr];
        row[32] = lsum;
    }
    __syncthreads();
    if (kh == 0) {
        const float* row = &MG[strip][l][0];
        lsum += row[32];
        lsum += __shfl_xor(lsum, 32);  // combine lane halves (complementary k offsets)
        const int b = bh >> 4, hd = bh & 15;
        float inv = 1.0f / lsum;
        #pragma unroll
        for (int dt2 = 0; dt2 < 2; ++dt2) {
            #pragma unroll
            for (int g = 0; g < 4; ++g) {
                s16x4 o;
                #pragma unroll
                for (int i = 0; i < 4; ++i)
                    o[i] = f2bf((O[dt2][g * 4 + i] + row[dt2 * 16 + g * 4 + i]) * inv);
                const int d = dt2 * 32 + 8 * g + 4 * h;
                *(s16x4*)&obf[(long)(b * 2048 + qlane) * 1024 + hd * 64 + d] = o;
            }
        }
    }
}

// ---------------- launch ----------------

extern "C" void kernel_launch(void* const* d_in, const int* in_sizes, int n_in,
                              void* d_out, int out_size, void* d_ws, size_t ws_size,
                              hipStream_t stream) {
    const float* x = (const float*)d_in[0];
    const float* qkv_w = (const float*)d_in[1];
    const float* qkv_b = (const float*)d_in[2];
    const float* proj_w = (const float*)d_in[3];
    const float* proj_b = (const float*)d_in[4];

    float* out = (float*)d_out;
    float* kout = out + 4194304;
    float* vout = out + 8388608;

    short* x_bf = (short*)d_ws;           // 4194304 shorts
    short* wT1 = x_bf + 4194304;          // 3145728
    short* wT2 = wT1 + 3145728;           // 1048576
    short* q_bf = wT2 + 1048576;          // 4194304
    short* k_bf = q_bf + 4194304;         // 4194304
    short* vT_bf = k_bf + 4194304;        // 4194304 ([B,H,D,S])
    short* o_bf = x_bf;                   // alias: x_bf dead after GEMM1

    fused_prepass<<<6144, 256, 0, stream>>>(x, x_bf, qkv_w, wT1, proj_w, wT2);

    gemm_bf16<1><<<768, 256, 0, stream>>>(x_bf, wT1, qkv_b, 4096, 3072, 1024,
                                          nullptr, q_bf, k_bf, vT_bf, kout, vout);

    attn_kernel<<<512, 512, 0, stream>>>(q_bf, k_bf, vT_bf, o_bf);

    gemm_bf16<2><<<256, 256, 0, stream>>>(o_bf, wT2, proj_b, 4096, 1024, 1024,
                                          out, nullptr, nullptr, nullptr, nullptr, nullptr);
}

// Round 22
// 99.688 us; speedup vs baseline: 1.1193x; 1.1193x over previous
//
#include <hip/hip_runtime.h>
#include <hip/hip_bf16.h>

// Shapes (fixed): B=2, S=2048, E=1024, H=16, D=64
// d_out: out[4194304] fp32 | k[4194304] fp32 [B,H,S,D] | v[4194304] fp32 [B,H,S,D]
// ws: x_bf | wT1 | wT2 | q_bf | k_bf | vT_bf ; o_bf aliases x_bf.

typedef __attribute__((ext_vector_type(4))) float f32x4;
typedef __attribute__((ext_vector_type(16))) float f32x16;
typedef __attribute__((ext_vector_type(8))) short s16x8;
typedef __attribute__((ext_vector_type(4))) short s16x4;

__device__ __forceinline__ short f2bf(float f) {
    union { float f; unsigned u; } x{f};
    unsigned r = x.u + 0x7fff + ((x.u >> 16) & 1);
    return (short)(r >> 16);
}

__device__ __forceinline__ void gload_lds16(const void* g, void* l) {
    __builtin_amdgcn_global_load_lds(
        (const __attribute__((address_space(1))) void*)g,
        (__attribute__((address_space(3))) void*)l, 16, 0, 0);
}

// ---------------- fused pre-pass (1 launch) ----------------
// blocks [0,2048):        x fp32 -> x_bf (8 elems/thread)
// blocks [2048,5120):     qkv_w [1024][3072] -> wT1 [3072][1024] bf16
// blocks [5120,6144):     proj_w [1024][1024] -> wT2 [1024][1024] bf16
__global__ __launch_bounds__(256) void fused_prepass(const float* __restrict__ x,
                                                     short* __restrict__ x_bf,
                                                     const float* __restrict__ qkv_w,
                                                     short* __restrict__ wT1,
                                                     const float* __restrict__ proj_w,
                                                     short* __restrict__ wT2) {
    __shared__ float tile[32][33];
    const int bid = blockIdx.x, tid = threadIdx.x;
    if (bid < 2048) {
        int i = (bid * 256 + tid) * 8;
        f32x4 a = *(const f32x4*)&x[i];
        f32x4 b = *(const f32x4*)&x[i + 4];
        s16x8 o;
        #pragma unroll
        for (int j = 0; j < 4; ++j) o[j] = f2bf(a[j]);
        #pragma unroll
        for (int j = 0; j < 4; ++j) o[j + 4] = f2bf(b[j]);
        *(s16x8*)&x_bf[i] = o;
        return;
    }
    const float* in;
    short* out;
    int K = 1024, N, n0, k0;
    if (bid < 5120) {
        int blk = bid - 2048;
        in = qkv_w; out = wT1; N = 3072;
        n0 = (blk % 96) * 32; k0 = (blk / 96) * 32;
    } else {
        int blk = bid - 5120;
        in = proj_w; out = wT2; N = 1024;
        n0 = (blk & 31) * 32; k0 = (blk >> 5) * 32;
    }
    const int tx = tid & 31, ty = tid >> 5;  // 32 x 8
    #pragma unroll
    for (int r = 0; r < 4; ++r)
        tile[ty + r * 8][tx] = in[(long)(k0 + ty + r * 8) * N + n0 + tx];
    __syncthreads();
    #pragma unroll
    for (int r = 0; r < 4; ++r)
        out[(long)(n0 + ty + r * 8) * K + k0 + tx] = f2bf(tile[tx][ty + r * 8]);
}

// ---------------- GEMM1 (round-19 exact: 128x128, BK=64, single-buffer, swizzle) -------
// A: [M][K] bf16, Bt: [N][K] bf16. qkv epilogue (q/k/v scatter + vT).
// Round-21 lesson (m99/m100/m132 confirmed): dbuf at 64 KB LDS loses to single-buffer at
// 32 KB (3 blocks/CU of implicit overlap beat explicit pipelining at 2 blocks/CU).
__global__ __launch_bounds__(256) void gemm1_bf16(
    const short* __restrict__ A, const short* __restrict__ Bt,
    const float* __restrict__ bias, int M, int N, int K,
    short* __restrict__ qbf, short* __restrict__ kbf, short* __restrict__ vbfT,
    float* __restrict__ kout, float* __restrict__ vout) {
    __shared__ __align__(16) short As[128 * 64];
    __shared__ __align__(16) short Bs[128 * 64];
    const int tid = threadIdx.x;
    const int l = tid & 63, w = tid >> 6;
    const int lr = l >> 4, lc = l & 15;
    const int wm = w >> 1, wn = w & 1;
    const int bid = blockIdx.x;
    const int xcd = bid & 7, s = bid >> 3;
    const int bx = (xcd & 1) * 12 + s % 12, by = (xcd >> 1) * 8 + s / 12;
    const int m0 = by * 128, n0 = bx * 128;

    f32x4 acc[4][4] = {};

    for (int kb = 0; kb < K; kb += 64) {
        __syncthreads();
        // stage: 1024 chunks of 16B per tile; chunk c -> row c>>3,
        // phys seg c&7 holds logical seg (c&7)^(row&7)   (XOR-swizzle both-sides)
        #pragma unroll
        for (int j = 0; j < 4; ++j) {
            const int c = tid + 256 * j;
            const int row = c >> 3;
            const int lseg = (c & 7) ^ (row & 7);
            gload_lds16(A + (long)(m0 + row) * K + kb + lseg * 8, As + c * 8);
            gload_lds16(Bt + (long)(n0 + row) * K + kb + lseg * 8, Bs + c * 8);
        }
        __syncthreads();
        #pragma unroll
        for (int kh = 0; kh < 2; ++kh) {
            s16x8 af[4], bfr[4];
            #pragma unroll
            for (int mi = 0; mi < 4; ++mi) {
                const int row = wm * 64 + mi * 16 + lc;
                af[mi] = *(const s16x8*)&As[row * 64 + (((kh * 4 + lr) ^ (lc & 7)) * 8)];
            }
            #pragma unroll
            for (int ni = 0; ni < 4; ++ni) {
                const int row = wn * 64 + ni * 16 + lc;
                bfr[ni] = *(const s16x8*)&Bs[row * 64 + (((kh * 4 + lr) ^ (lc & 7)) * 8)];
            }
            #pragma unroll
            for (int mi = 0; mi < 4; ++mi)
                #pragma unroll
                for (int ni = 0; ni < 4; ++ni)
                    acc[mi][ni] = __builtin_amdgcn_mfma_f32_16x16x32_bf16(
                        af[mi], bfr[ni], acc[mi][ni], 0, 0, 0);
        }
    }

    #pragma unroll
    for (int mi = 0; mi < 4; ++mi) {
        #pragma unroll
        for (int ni = 0; ni < 4; ++ni) {
            int col = n0 + wn * 64 + ni * 16 + lc;
            float bv = bias[col];
            int sec = col >> 10, rem = col & 1023;
            int h = rem >> 6, d = rem & 63;
            int row0 = m0 + wm * 64 + mi * 16 + lr * 4;
            int b = row0 >> 11, s0 = row0 & 2047;
            long idxSD = ((long)((b << 4) + h) * 2048 + s0) * 64 + d;
            if (sec == 0) {
                #pragma unroll
                for (int i = 0; i < 4; ++i) {
                    float val = acc[mi][ni][i] + bv;
                    // bake attn scale 1/8 and log2(e) for exp2-domain softmax
                    qbf[idxSD + (long)i * 64] = f2bf(val * 0.1803368801111244f);
                }
            } else if (sec == 1) {
                #pragma unroll
                for (int i = 0; i < 4; ++i) {
                    float val = acc[mi][ni][i] + bv;
                    kout[idxSD + (long)i * 64] = val;
                    kbf[idxSD + (long)i * 64] = f2bf(val);
                }
            } else {
                s16x4 pk;
                #pragma unroll
                for (int i = 0; i < 4; ++i) {
                    float val = acc[mi][ni][i] + bv;
                    vout[idxSD + (long)i * 64] = val;
                    pk[i] = f2bf(val);
                }
                *(s16x4*)&vbfT[((long)((b << 4) + h) * 64 + d) * 2048 + s0] = pk;
            }
        }
    }
}

// ---------------- GEMM2 (k-split 8-wave + ADD merge; fixes 1-block/CU starvation) ------
// grid 256 blocks = 1/CU -> plain 256-thr version had only 4 waves/CU. 8 waves; group
// grp = wv>>2 handles K-half [grp*512, grp*512+512) with its own LDS pair (64 KB total,
// fine at 1 block/CU). Per-wave k-iters halve; waves/CU double. Merge: grp1 dumps its
// 64x64 fp32 acc into the dead staging LDS (4 waves x 4096 floats), barrier, grp0 adds
// and runs the bias epilogue. NO min-waves launch bound (round-20's (512,4) forced
// VGPR 64 -> spills; default keeps ~88).
__global__ __launch_bounds__(512) void gemm2_bf16(
    const short* __restrict__ A, const short* __restrict__ Bt,
    const float* __restrict__ bias, int M, int N, int K,
    float* __restrict__ outf) {
    __shared__ __align__(16) short As[2][128 * 64];
    __shared__ __align__(16) short Bs[2][128 * 64];
    const int tid = threadIdx.x;
    const int l = tid & 63, wv = tid >> 6;
    const int grp = wv >> 2, w = wv & 3;
    const int lr = l >> 4, lc = l & 15;
    const int wm = w >> 1, wn = w & 1;
    const int bid = blockIdx.x;
    const int xcd = bid & 7, s = bid >> 3;
    const int bx = (xcd & 1) * 4 + (s & 3), by = (xcd >> 1) * 8 + (s >> 2);
    const int m0 = by * 128, n0 = bx * 128;
    const int gtid = tid & 255;

    f32x4 acc[4][4] = {};

    for (int it = 0; it < 8; ++it) {              // 8 iters of BK=64 per k-group
        const int kb = grp * 512 + it * 64;
        __syncthreads();
        #pragma unroll
        for (int j = 0; j < 4; ++j) {
            const int c = gtid + 256 * j;
            const int row = c >> 3;
            const int lseg = (c & 7) ^ (row & 7);
            gload_lds16(A + (long)(m0 + row) * K + kb + lseg * 8, &As[grp][c * 8]);
            gload_lds16(Bt + (long)(n0 + row) * K + kb + lseg * 8, &Bs[grp][c * 8]);
        }
        __syncthreads();
        #pragma unroll
        for (int kh = 0; kh < 2; ++kh) {
            s16x8 af[4], bfr[4];
            #pragma unroll
            for (int mi = 0; mi < 4; ++mi) {
                const int row = wm * 64 + mi * 16 + lc;
                af[mi] = *(const s16x8*)&As[grp][row * 64 + (((kh * 4 + lr) ^ (lc & 7)) * 8)];
            }
            #pragma unroll
            for (int ni = 0; ni < 4; ++ni) {
                const int row = wn * 64 + ni * 16 + lc;
                bfr[ni] = *(const s16x8*)&Bs[grp][row * 64 + (((kh * 4 + lr) ^ (lc & 7)) * 8)];
            }
            #pragma unroll
            for (int mi = 0; mi < 4; ++mi)
                #pragma unroll
                for (int ni = 0; ni < 4; ++ni)
                    acc[mi][ni] = __builtin_amdgcn_mfma_f32_16x16x32_bf16(
                        af[mi], bfr[ni], acc[mi][ni], 0, 0, 0);
        }
    }

    // k-group ADD merge through the dead staging LDS
    __syncthreads();
    float* reg = (w < 2) ? (float*)&As[w][0] : (float*)&Bs[w - 2][0];  // 4096 floats/wave
    if (grp == 1) {
        #pragma unroll
        for (int mi = 0; mi < 4; ++mi)
            #pragma unroll
            for (int ni = 0; ni < 4; ++ni)
                #pragma unroll
                for (int i = 0; i < 4; ++i)
                    reg[(mi * 16 + lr * 4 + i) * 64 + ni * 16 + lc] = acc[mi][ni][i];
    }
    __syncthreads();
    if (grp == 1) return;
    #pragma unroll
    for (int mi = 0; mi < 4; ++mi)
        #pragma unroll
        for (int ni = 0; ni < 4; ++ni)
            #pragma unroll
            for (int i = 0; i < 4; ++i)
                acc[mi][ni][i] += reg[(mi * 16 + lr * 4 + i) * 64 + ni * 16 + lc];

    #pragma unroll
    for (int mi = 0; mi < 4; ++mi) {
        #pragma unroll
        for (int ni = 0; ni < 4; ++ni) {
            int col = n0 + wn * 64 + ni * 16 + lc;
            float bv = bias[col];
            #pragma unroll
            for (int i = 0; i < 4; ++i) {
                int row = m0 + wm * 64 + mi * 16 + lr * 4 + i;
                outf[(long)row * N + col] = acc[mi][ni][i] + bv;
            }
        }
    }
}

// ---------------- flash attention (round-19: 8 waves, k-split + ADD merge) -------------
__global__ __launch_bounds__(512, 4) void attn_kernel(const short* __restrict__ qbf,
                                                      const short* __restrict__ kbf,
                                                      const short* __restrict__ vbfT,
                                                      short* __restrict__ obf) {
    const int bid = blockIdx.x;
    const int xcd = bid & 7, r = bid >> 3;      // 64 slots per XCD
    const int head_local = r & 3, q16 = r >> 2; // q16 in 0..15
    const int qt = (q16 < 8) ? (q16 + 8) : (15 - q16);  // CU slot-pair qt sums = 15
    const int bh = xcd * 4 + head_local;
    const int tid = threadIdx.x;
    const int wv = tid >> 6, l = tid & 63;      // wv in 0..7
    const int strip = wv & 3, kh = wv >> 2;     // q-strip, key-half
    const int h = l >> 5;                        // lane half
    const int l8 = l & 7;
    const int q0 = qt * 128 + strip * 32;        // this wave's 32-q strip
    const int qlane = q0 + (l & 31);
    const long baseSD = (long)bh * 2048 * 64;   // q,k: [S][64]
    const long baseDS = (long)bh * 64 * 2048;   // vT:  [64][S]

    __shared__ __align__(16) short Ks[2][64 * 64];  // swizzled K tile   (8 KB x2)
    __shared__ __align__(16) short Vs[2][64 * 64];  // swizzled V^T tile (8 KB x2)
    __shared__ __align__(16) float MG[4][64][36];   // merge: O[32] | lsum (36 KB, one-time)

    const int sSub = l >> 3;
    const int sChunk = (l & 7) ^ sSub;
    auto stage = [&](int kt, int nb) {
        const int k0 = kt * 64;
        const int r0 = wv * 8 + sSub;
        gload_lds16(kbf + baseSD + (long)(k0 + r0) * 64 + sChunk * 8,
                    &Ks[nb][(wv * 8) * 64]);
        gload_lds16(vbfT + baseDS + (long)r0 * 2048 + k0 + sChunk * 8,
                    &Vs[nb][(wv * 8) * 64]);
    };

    // Q fragments (B-operand, 32x32x16): lane holds col q = qlane, kdim d = dd*16 + h*8 + j
    s16x8 qf[4];
    #pragma unroll
    for (int dd = 0; dd < 4; ++dd)
        qf[dd] = *(const s16x8*)&qbf[baseSD + (long)qlane * 64 + dd * 16 + h * 8];

    f32x4 lacc = {};                   // 4 independent partial-sum accumulators
    f32x16 O[2] = {};                  // O^T: O[dt2][rr] = O[d = dt2*32+(rr&3)+8*(rr>>2)+4h][qlane]

    const int nkt = 2 * qt + 2;        // k-tiles covering rows 0..qt*128+127

    stage(0, 0);
    __syncthreads();                   // drains vmcnt -> buf0 ready
    int cur = 0;

    for (int kt = 0; kt < nkt; ++kt) {
        if (kt + 1 < nkt) stage(kt + 1, cur ^ 1);
        const int kbase = kt * 64 + kh * 32;   // this wave's 32-key half

        if (kbase <= q0 + 31) {        // half has unmasked keys for this strip
            const short* Kb = Ks[cur];
            const short* Vb = Vs[cur];
            // QK: S^T[32k x 32q] accumulated over d (keys kbase..kbase+31)
            f32x16 z = {};
            #pragma unroll
            for (int dd = 0; dd < 4; ++dd) {
                s16x8 kf = *(const s16x8*)&Kb[(kh * 32 + (l & 31)) * 64 +
                                              (((2 * dd + h) ^ l8) * 8)];
                z = __builtin_amdgcn_mfma_f32_32x32x16_bf16(kf, qf[dd], z, 0, 0, 0);
            }
            // causal mask: k = kbase + (rr&3)+8*(rr>>2)+4h, q = qlane
            if (kbase + 31 > q0) {
                #pragma unroll
                for (int rr = 0; rr < 16; ++rr) {
                    int kpos = kbase + (rr & 3) + 8 * (rr >> 2) + 4 * h;
                    if (kpos > qlane) z[rr] = -INFINITY;
                }
            }
            // static softmax: p = exp2(s'); exp2(-inf) = 0 handles the mask
            float p[16];
            #pragma unroll
            for (int rr = 0; rr < 16; ++rr) {
                p[rr] = __builtin_amdgcn_exp2f(z[rr]);
                lacc[rr & 3] += p[rr];
            }
            // PV per 16-k fragment f (k base fb = kh*32 + f*16), pi-permuted kdim:
            //   B = packed own p[f*8..f*8+7] via v_cvt_pk_bf16_f32 (builtin, RNE);
            //   A = V^T rows, two b64 at k = fb+4h and fb+8+4h.
            #pragma unroll
            for (int f = 0; f < 2; ++f) {
                union { __hip_bfloat162 b2[4]; s16x8 v; } pk;
                #pragma unroll
                for (int j = 0; j < 4; ++j)
                    pk.b2[j] = __float22bfloat162_rn(
                        make_float2(p[f * 8 + 2 * j], p[f * 8 + 2 * j + 1]));
                const int c0 = kh * 4 + f * 2;        // logical chunk of fb
                #pragma unroll
                for (int dt2 = 0; dt2 < 2; ++dt2) {
                    const short* vr = &Vb[(dt2 * 32 + (l & 31)) * 64];
                    s16x8 vf;
                    *(s16x4*)&vf = *(const s16x4*)&vr[(c0 ^ l8) * 8 + 4 * h];
                    *(((s16x4*)&vf) + 1) = *(const s16x4*)&vr[((c0 + 1) ^ l8) * 8 + 4 * h];
                    O[dt2] = __builtin_amdgcn_mfma_f32_32x32x16_bf16(vf, pk.v,
                                                                     O[dt2], 0, 0, 0);
                }
            }
        }
        __syncthreads();               // all done with buf[cur]; stage(kt+1) drained
        cur ^= 1;
    }

    // ---- k-half merge (pure ADD: static softmax => O, lsum are sums over k) ----
    float lsum = (lacc[0] + lacc[1]) + (lacc[2] + lacc[3]);
    if (kh == 1) {
        float* row = &MG[strip][l][0];
        #pragma unroll
        for (int dt2 = 0; dt2 < 2; ++dt2)
            #pragma unroll
            for (int rr = 0; rr < 16; ++rr)
                row[dt2 * 16 + rr] = O[dt2][rr];
        row[32] = lsum;
    }
    __syncthreads();
    if (kh == 0) {
        const float* row = &MG[strip][l][0];
        lsum += row[32];
        lsum += __shfl_xor(lsum, 32);  // combine lane halves (complementary k offsets)
        const int b = bh >> 4, hd = bh & 15;
        float inv = 1.0f / lsum;
        #pragma unroll
        for (int dt2 = 0; dt2 < 2; ++dt2) {
            #pragma unroll
            for (int g = 0; g < 4; ++g) {
                s16x4 o;
                #pragma unroll
                for (int i = 0; i < 4; ++i)
                    o[i] = f2bf((O[dt2][g * 4 + i] + row[dt2 * 16 + g * 4 + i]) * inv);
                const int d = dt2 * 32 + 8 * g + 4 * h;
                *(s16x4*)&obf[(long)(b * 2048 + qlane) * 1024 + hd * 64 + d] = o;
            }
        }
    }
}

// ---------------- launch ----------------

extern "C" void kernel_launch(void* const* d_in, const int* in_sizes, int n_in,
                              void* d_out, int out_size, void* d_ws, size_t ws_size,
                              hipStream_t stream) {
    const float* x = (const float*)d_in[0];
    const float* qkv_w = (const float*)d_in[1];
    const float* qkv_b = (const float*)d_in[2];
    const float* proj_w = (const float*)d_in[3];
    const float* proj_b = (const float*)d_in[4];

    float* out = (float*)d_out;
    float* kout = out + 4194304;
    float* vout = out + 8388608;

    short* x_bf = (short*)d_ws;           // 4194304 shorts
    short* wT1 = x_bf + 4194304;          // 3145728
    short* wT2 = wT1 + 3145728;           // 1048576
    short* q_bf = wT2 + 1048576;          // 4194304
    short* k_bf = q_bf + 4194304;         // 4194304
    short* vT_bf = k_bf + 4194304;        // 4194304 ([B,H,D,S])
    short* o_bf = x_bf;                   // alias: x_bf dead after GEMM1

    fused_prepass<<<6144, 256, 0, stream>>>(x, x_bf, qkv_w, wT1, proj_w, wT2);

    gemm1_bf16<<<768, 256, 0, stream>>>(x_bf, wT1, qkv_b, 4096, 3072, 1024,
                                        q_bf, k_bf, vT_bf, kout, vout);

    attn_kernel<<<512, 512, 0, stream>>>(q_bf, k_bf, vT_bf, o_bf);

    gemm2_bf16<<<256, 512, 0, stream>>>(o_bf, wT2, proj_b, 4096, 1024, 1024, out);
}